// Round 11
// baseline (102.121 us; speedup 1.0000x reference)
//
#include <hip/hip_runtime.h>
#include <hip/hip_bf16.h>

#define N_NODES 262144
#define N_GRAPHS 256
#define DMODEL 256
#define LOG2_F 0.69314718055994530942f

typedef __attribute__((ext_vector_type(4))) float f32x4;
typedef __attribute__((ext_vector_type(8))) short short8;

__device__ __forceinline__ short bf(float x) {
    __hip_bfloat16 h = __float2bfloat16(x);
    return __builtin_bit_cast(short, h);
}

__device__ __forceinline__ short8 cvt8(f32x4 lo, f32x4 hi) {
    short8 a;
    a[0] = bf(lo[0]); a[1] = bf(lo[1]); a[2] = bf(lo[2]); a[3] = bf(lo[3]);
    a[4] = bf(hi[0]); a[5] = bf(hi[1]); a[6] = bf(hi[2]); a[7] = bf(hi[3]);
    return a;
}

__device__ __forceinline__ void mfma8(short8 a, const char* bb, f32x4* acc) {
#pragma unroll
    for (int nt = 0; nt < 8; ++nt) {
        short8 bfrag = *reinterpret_cast<const short8*>(bb + nt * 1024);
        acc[nt] = __builtin_amdgcn_mfma_f32_16x16x32_bf16(a, bfrag, acc[nt], 0, 0, 0);
    }
}

// Pack g_enc (fp32 [G=256][D=256]) into bf16 B-fragments in MFMA lane order.
// chunk c = ks*16 + ntile (128 chunks of 1KB). Within chunk: lane*16B.
__global__ void pack_b_kernel(const float* __restrict__ g_enc,
                              short* __restrict__ bout) {
    int b = blockIdx.x;        // 0..127
    int lane = threadIdx.x;    // 0..63
    int ks = b >> 4, nt = b & 15;
    int g = nt * 16 + (lane & 15);
    int k = ks * 32 + (lane >> 4) * 8;
    const float* src = g_enc + g * DMODEL + k;
    short8 v;
#pragma unroll
    for (int j = 0; j < 8; ++j) v[j] = bf(src[j]);
    reinterpret_cast<short8*>(bout)[b * 64 + lane] = v;
}

// R11: 1024-thread blocks (16 waves = 4 waves/SIMD) sharing ONE 128KB B
// staging -> doubles TLP vs R9/R10 (which ran 2 waves/SIMD and appeared
// latency-bound at ~90us). Per-wave structure = R9's frugal 16rx128c tile:
// acc[8] (32 regs) + 4 named slots, group-of-4-ks pipeline, cross-pass
// prefetch ((pass+1)&7 wraps). 16 waves = 8 row-stripes x 2 col-halves;
// pass = 128 rows; 8 passes x 256 blocks = 262144 rows.
__global__ __launch_bounds__(1024, 1) void mvgrl_main(
    const float* __restrict__ l_enc, const int* __restrict__ batch,
    const short* __restrict__ bpack, double* __restrict__ partials) {
    extern __shared__ char lds_raw[];  // 128KB: full B in fragment order

    const int tid = threadIdx.x;
    const int lane = tid & 63;
    const int wave = tid >> 6;   // 0..15
    const int wrow = wave & 7;   // row stripe (16 rows each)
    const int chalf = wave >> 3; // column half (128 cols each)

    // ---- stage entire B (128KB) into LDS once ----
    {
        const short8* bp = reinterpret_cast<const short8*>(bpack);
        short8* lb = reinterpret_cast<short8*>(lds_raw);
#pragma unroll
        for (int c = 0; c < 8; ++c) {
            int chunk = wave + c * 16;
            lb[chunk * 64 + lane] = bp[chunk * 64 + lane];
        }
    }
    __syncthreads();
    // no further barriers until final reduction

    const int row_blk = blockIdx.x * 1024;
    const char* ldsB = lds_raw + chalf * 8192 + lane * 16;
    double dSall = 0.0, dSpq = 0.0, dSpr = 0.0;

    // Named pipeline slots (never runtime-indexed)
    f32x4 s0l, s0h, s1l, s1h, s2l, s2h, s3l, s3h;

    const int kofs = (lane >> 4) * 8;
    const float* arow = l_enc +
        (size_t)(row_blk + wrow * 16 + (lane & 15)) * DMODEL + kofs;
    s0l = *reinterpret_cast<const f32x4*>(arow + 0);
    s0h = *reinterpret_cast<const f32x4*>(arow + 4);
    s1l = *reinterpret_cast<const f32x4*>(arow + 32);
    s1h = *reinterpret_cast<const f32x4*>(arow + 36);
    s2l = *reinterpret_cast<const f32x4*>(arow + 64);
    s2h = *reinterpret_cast<const f32x4*>(arow + 68);
    s3l = *reinterpret_cast<const f32x4*>(arow + 96);
    s3h = *reinterpret_cast<const f32x4*>(arow + 100);

#pragma unroll 1
    for (int pass = 0; pass < 8; ++pass) {
        const int rowbase = row_blk + pass * 128 + wrow * 16;
        const int rsub = (lane >> 4) * 4;
        int bv0 = batch[rowbase + rsub + 0];
        int bv1 = batch[rowbase + rsub + 1];
        int bv2 = batch[rowbase + rsub + 2];
        int bv3 = batch[rowbase + rsub + 3];

        const float* arow_next = l_enc +
            (size_t)(row_blk + ((pass + 1) & 7) * 128 + wrow * 16 + (lane & 15)) *
                DMODEL + kofs;

        f32x4 acc[8];
#pragma unroll
        for (int n = 0; n < 8; ++n) acc[n] = (f32x4){0.f, 0.f, 0.f, 0.f};

#pragma unroll 1
        for (int g = 0; g < 2; ++g) {
            // group g consumes slots (ks = g*4 .. g*4+3) and refills them
            // with: g==0 -> this pass ks 4..7; g==1 -> next pass ks 0..3.
            const float* src = (g == 0) ? (arow + 128) : arow_next;
            const char* lb = ldsB + (size_t)g * 4 * 16384;
            {
                short8 a = cvt8(s0l, s0h);
                s0l = *reinterpret_cast<const f32x4*>(src + 0);
                s0h = *reinterpret_cast<const f32x4*>(src + 4);
                mfma8(a, lb + 0 * 16384, acc);
            }
            {
                short8 a = cvt8(s1l, s1h);
                s1l = *reinterpret_cast<const f32x4*>(src + 32);
                s1h = *reinterpret_cast<const f32x4*>(src + 36);
                mfma8(a, lb + 1 * 16384, acc);
            }
            {
                short8 a = cvt8(s2l, s2h);
                s2l = *reinterpret_cast<const f32x4*>(src + 64);
                s2h = *reinterpret_cast<const f32x4*>(src + 68);
                mfma8(a, lb + 2 * 16384, acc);
            }
            {
                short8 a = cvt8(s3l, s3h);
                s3l = *reinterpret_cast<const f32x4*>(src + 96);
                s3h = *reinterpret_cast<const f32x4*>(src + 100);
                mfma8(a, lb + 3 * 16384, acc);
            }
        }
        arow = arow_next;

        // ---- epilogue: q = softplus(r) - log2 ----
        // C/D layout: col = chalf*128 + nt*16 + (lane&15),
        //             row = rowbase + rsub + rg
        float Sall = 0.f, Spq = 0.f, Spr = 0.f;
        const int colbase = chalf * 128 + (lane & 15);
#pragma unroll
        for (int nt = 0; nt < 8; ++nt) {
            const int col = colbase + nt * 16;
            f32x4 av = acc[nt];
            {
                float r = av[0];
                float q = fmaxf(r, 0.f) - LOG2_F + __logf(1.f + __expf(-fabsf(r)));
                Sall += q; if (col == bv0) { Spq += q; Spr += r; }
            }
            {
                float r = av[1];
                float q = fmaxf(r, 0.f) - LOG2_F + __logf(1.f + __expf(-fabsf(r)));
                Sall += q; if (col == bv1) { Spq += q; Spr += r; }
            }
            {
                float r = av[2];
                float q = fmaxf(r, 0.f) - LOG2_F + __logf(1.f + __expf(-fabsf(r)));
                Sall += q; if (col == bv2) { Spq += q; Spr += r; }
            }
            {
                float r = av[3];
                float q = fmaxf(r, 0.f) - LOG2_F + __logf(1.f + __expf(-fabsf(r)));
                Sall += q; if (col == bv3) { Spq += q; Spr += r; }
            }
        }
        dSall += (double)Sall;
        dSpq += (double)Spq;
        dSpr += (double)Spr;
    }

    // ---- reduction: wave shuffle -> LDS -> block partial ----
#pragma unroll
    for (int off = 32; off; off >>= 1) {
        dSall += __shfl_xor(dSall, off);
        dSpq += __shfl_xor(dSpq, off);
        dSpr += __shfl_xor(dSpr, off);
    }
    __syncthreads();  // everyone done reading B before LDS reuse
    double* red = reinterpret_cast<double*>(lds_raw);
    if (lane == 0) {
        red[wave * 3 + 0] = dSall;
        red[wave * 3 + 1] = dSpq;
        red[wave * 3 + 2] = dSpr;
    }
    __syncthreads();
    if (tid == 0) {
        double a = 0, b = 0, c = 0;
#pragma unroll
        for (int w = 0; w < 16; ++w) {
            a += red[w * 3 + 0];
            b += red[w * 3 + 1];
            c += red[w * 3 + 2];
        }
        partials[blockIdx.x * 3 + 0] = a;
        partials[blockIdx.x * 3 + 1] = b;
        partials[blockIdx.x * 3 + 2] = c;
    }
}

__global__ void finalize_kernel(const double* __restrict__ p,
                                float* __restrict__ out) {
    int t = threadIdx.x;  // 256 threads, one partial-triple each
    double a = p[t * 3 + 0], b = p[t * 3 + 1], c = p[t * 3 + 2];
#pragma unroll
    for (int off = 32; off; off >>= 1) {
        a += __shfl_xor(a, off);
        b += __shfl_xor(b, off);
        c += __shfl_xor(c, off);
    }
    __shared__ double red[12];
    int lane = t & 63, w = t >> 6;
    if (lane == 0) { red[w * 3] = a; red[w * 3 + 1] = b; red[w * 3 + 2] = c; }
    __syncthreads();
    if (t == 0) {
        double A = 0, B = 0, C = 0;
#pragma unroll
        for (int i = 0; i < 4; ++i) {
            A += red[i * 3]; B += red[i * 3 + 1]; C += red[i * 3 + 2];
        }
        // neg_sum = S_all - S_posq ; pos_sum = S_posr - S_posq
        double neg = (A - B) / ((double)N_NODES * (double)(N_GRAPHS - 1));
        double pos = (C - B) / (double)N_NODES;
        out[0] = (float)(neg - pos);
    }
}

extern "C" void kernel_launch(void* const* d_in, const int* in_sizes, int n_in,
                              void* d_out, int out_size, void* d_ws,
                              size_t ws_size, hipStream_t stream) {
    const float* l_enc = (const float*)d_in[0];
    const float* g_enc = (const float*)d_in[1];
    const int* batch = (const int*)d_in[2];
    float* out = (float*)d_out;

    short* bpack = (short*)d_ws;                           // 128KB
    double* partials = (double*)((char*)d_ws + 131072);    // 256*3 doubles

    hipFuncSetAttribute(reinterpret_cast<const void*>(mvgrl_main),
                        hipFuncAttributeMaxDynamicSharedMemorySize, 131072);

    pack_b_kernel<<<128, 64, 0, stream>>>(g_enc, bpack);
    mvgrl_main<<<256, 1024, 131072, stream>>>(l_enc, batch, bpack, partials);
    finalize_kernel<<<1, 256, 0, stream>>>(partials, out);
}

// Round 13
// 89.927 us; speedup vs baseline: 1.1356x; 1.1356x over previous
//
#include <hip/hip_runtime.h>
#include <hip/hip_bf16.h>

#define N_NODES 262144
#define N_GRAPHS 256
#define DMODEL 256
#define LN2 0.6931471805599453094

typedef __attribute__((ext_vector_type(4))) float f32x4;
typedef __attribute__((ext_vector_type(8))) short short8;

__device__ __forceinline__ short bf(float x) {
    __hip_bfloat16 h = __float2bfloat16(x);
    return __builtin_bit_cast(short, h);
}

__device__ __forceinline__ short8 cvt8(f32x4 lo, f32x4 hi) {
    short8 a;
    a[0] = bf(lo[0]); a[1] = bf(lo[1]); a[2] = bf(lo[2]); a[3] = bf(lo[3]);
    a[4] = bf(hi[0]); a[5] = bf(hi[1]); a[6] = bf(hi[2]); a[7] = bf(hi[3]);
    return a;
}

// One bfrag read feeds TWO MFMAs (m0/m1 row-fragments) -> halves LDS traffic.
__device__ __forceinline__ void mfma16(short8 a0, short8 a1, const char* bb,
                                       f32x4* accA, f32x4* accB) {
#pragma unroll
    for (int nt = 0; nt < 8; ++nt) {
        short8 bfrag = *reinterpret_cast<const short8*>(bb + nt * 1024);
        accA[nt] = __builtin_amdgcn_mfma_f32_16x16x32_bf16(a0, bfrag, accA[nt], 0, 0, 0);
        accB[nt] = __builtin_amdgcn_mfma_f32_16x16x32_bf16(a1, bfrag, accB[nt], 0, 0, 0);
    }
}

// Per-element contribution in log2 units:
//   l2 = log2(1 + 2^(log2e * min(r,64)))  ==> softplus(r) = ln2 * l2  (exact id)
// Accumulate Sl2 (all), Sl2p (pos, via float-mask fma), Spr (pos r).
__device__ __forceinline__ void elem(float r, int col, int bv,
                                     float& Sl2, float& Sl2p, float& Spr) {
    float t = fminf(r, 64.f) * 1.44269504f;
    float l2 = __log2f(1.f + exp2f(t));
    Sl2 += l2;
    float m = (col == bv) ? 1.f : 0.f;
    Sl2p = fmaf(m, l2, Sl2p);
    Spr = fmaf(m, r, Spr);
}

// Pack g_enc (fp32 [G=256][D=256]) into bf16 B-fragments in MFMA lane order.
// chunk c = ks*16 + ntile (128 chunks of 1KB). Within chunk: lane*16B.
__global__ void pack_b_kernel(const float* __restrict__ g_enc,
                              short* __restrict__ bout) {
    int b = blockIdx.x;        // 0..127
    int lane = threadIdx.x;    // 0..63
    int ks = b >> 4, nt = b & 15;
    int g = nt * 16 + (lane & 15);
    int k = ks * 32 + (lane >> 4) * 8;
    const float* src = g_enc + g * DMODEL + k;
    short8 v;
#pragma unroll
    for (int j = 0; j < 8; ++j) v[j] = bf(src[j]);
    reinterpret_cast<short8*>(bout)[b * 64 + lane] = v;
}

// R13 = R12 with the compile fix (exp2f instead of __exp2f).
// R10 structure (32r x 128c per wave, mfma16, 8 waves, group pipeline)
// + lean base-2 epilogue (~10 VALU/elem vs ~14). Per-element -LOG2 and the
// ln2 scale are folded into finalize using exact counts (N*G elems, N pos).
__global__ __launch_bounds__(512, 1) void mvgrl_main(
    const float* __restrict__ l_enc, const int* __restrict__ batch,
    const short* __restrict__ bpack, double* __restrict__ partials) {
    extern __shared__ char lds_raw[];  // 128KB: full B in fragment order

    const int tid = threadIdx.x;
    const int lane = tid & 63;
    const int wave = tid >> 6;   // 0..7
    const int wrow = wave & 3;   // row stripe (32 rows each)
    const int chalf = wave >> 2; // column half (128 cols each)

    // ---- stage entire B (128KB) into LDS once ----
    {
        const short8* bp = reinterpret_cast<const short8*>(bpack);
        short8* lb = reinterpret_cast<short8*>(lds_raw);
#pragma unroll
        for (int c = 0; c < 16; ++c) {
            int chunk = wave + c * 8;
            lb[chunk * 64 + lane] = bp[chunk * 64 + lane];
        }
    }
    __syncthreads();
    // no further barriers until final reduction

    const int row_blk = blockIdx.x * 1024;
    const char* ldsB = lds_raw + chalf * 8192 + lane * 16;
    double dS0 = 0.0, dS1 = 0.0, dS2 = 0.0;

    // Named A-pipeline slots: e=even ks, o=odd ks; 0=m0 row-frag, 1=m1.
    f32x4 se0l, se0h, se1l, se1h, so0l, so0h, so1l, so1h;

    const int kofs = (lane >> 4) * 8;
    const float* arow = l_enc +
        (size_t)(row_blk + wrow * 32 + (lane & 15)) * DMODEL + kofs;
    const float* am1 = arow + 16 * DMODEL;
    se0l = *reinterpret_cast<const f32x4*>(arow + 0);
    se0h = *reinterpret_cast<const f32x4*>(arow + 4);
    se1l = *reinterpret_cast<const f32x4*>(am1 + 0);
    se1h = *reinterpret_cast<const f32x4*>(am1 + 4);
    so0l = *reinterpret_cast<const f32x4*>(arow + 32);
    so0h = *reinterpret_cast<const f32x4*>(arow + 36);
    so1l = *reinterpret_cast<const f32x4*>(am1 + 32);
    so1h = *reinterpret_cast<const f32x4*>(am1 + 36);

#pragma unroll 1
    for (int pass = 0; pass < 8; ++pass) {
        const int rowbase = row_blk + pass * 128 + wrow * 32;
        const int rsub = (lane >> 4) * 4;
        int bvA0 = batch[rowbase + rsub + 0];
        int bvA1 = batch[rowbase + rsub + 1];
        int bvA2 = batch[rowbase + rsub + 2];
        int bvA3 = batch[rowbase + rsub + 3];
        int bvB0 = batch[rowbase + 16 + rsub + 0];
        int bvB1 = batch[rowbase + 16 + rsub + 1];
        int bvB2 = batch[rowbase + 16 + rsub + 2];
        int bvB3 = batch[rowbase + 16 + rsub + 3];

        const float* arow_next = l_enc +
            (size_t)(row_blk + ((pass + 1) & 7) * 128 + wrow * 32 + (lane & 15)) *
                DMODEL + kofs;

        f32x4 accA[8], accB[8];
#pragma unroll
        for (int n = 0; n < 8; ++n) {
            accA[n] = (f32x4){0.f, 0.f, 0.f, 0.f};
            accB[n] = (f32x4){0.f, 0.f, 0.f, 0.f};
        }

#pragma unroll 1
        for (int g = 0; g < 4; ++g) {
            // refill source: group g+1's ks pair (g=3 -> next pass ks0/1)
            const float* srcE = (g < 3) ? (arow + (2 * g + 2) * 32) : arow_next;
            const float* srcEm1 = srcE + 16 * DMODEL;
            // even ks = 2g
            {
                short8 a0 = cvt8(se0l, se0h);
                short8 a1 = cvt8(se1l, se1h);
                se0l = *reinterpret_cast<const f32x4*>(srcE + 0);
                se0h = *reinterpret_cast<const f32x4*>(srcE + 4);
                se1l = *reinterpret_cast<const f32x4*>(srcEm1 + 0);
                se1h = *reinterpret_cast<const f32x4*>(srcEm1 + 4);
                mfma16(a0, a1, ldsB + (size_t)(2 * g) * 16384, accA, accB);
            }
            // odd ks = 2g+1
            {
                short8 a0 = cvt8(so0l, so0h);
                short8 a1 = cvt8(so1l, so1h);
                so0l = *reinterpret_cast<const f32x4*>(srcE + 32);
                so0h = *reinterpret_cast<const f32x4*>(srcE + 36);
                so1l = *reinterpret_cast<const f32x4*>(srcEm1 + 32);
                so1h = *reinterpret_cast<const f32x4*>(srcEm1 + 36);
                mfma16(a0, a1, ldsB + (size_t)(2 * g + 1) * 16384, accA, accB);
            }
        }
        arow = arow_next;

        // ---- lean epilogue (log2 units) ----
        // C/D: col = chalf*128 + nt*16 + (lane&15),
        //      rowA = rowbase + rsub + rg ; rowB = rowA + 16
        float Sl2 = 0.f, Sl2p = 0.f, Spr = 0.f;
        const int colbase = chalf * 128 + (lane & 15);
#pragma unroll
        for (int nt = 0; nt < 8; ++nt) {
            const int col = colbase + nt * 16;
            f32x4 avA = accA[nt];
            f32x4 avB = accB[nt];
            elem(avA[0], col, bvA0, Sl2, Sl2p, Spr);
            elem(avA[1], col, bvA1, Sl2, Sl2p, Spr);
            elem(avA[2], col, bvA2, Sl2, Sl2p, Spr);
            elem(avA[3], col, bvA3, Sl2, Sl2p, Spr);
            elem(avB[0], col, bvB0, Sl2, Sl2p, Spr);
            elem(avB[1], col, bvB1, Sl2, Sl2p, Spr);
            elem(avB[2], col, bvB2, Sl2, Sl2p, Spr);
            elem(avB[3], col, bvB3, Sl2, Sl2p, Spr);
        }
        dS0 += (double)Sl2;
        dS1 += (double)Sl2p;
        dS2 += (double)Spr;
    }

    // ---- reduction: wave shuffle -> LDS -> block partial ----
#pragma unroll
    for (int off = 32; off; off >>= 1) {
        dS0 += __shfl_xor(dS0, off);
        dS1 += __shfl_xor(dS1, off);
        dS2 += __shfl_xor(dS2, off);
    }
    __syncthreads();  // everyone done reading B before LDS reuse
    double* red = reinterpret_cast<double*>(lds_raw);
    if (lane == 0) {
        red[wave * 3 + 0] = dS0;
        red[wave * 3 + 1] = dS1;
        red[wave * 3 + 2] = dS2;
    }
    __syncthreads();
    if (tid == 0) {
        double a = 0, b = 0, c = 0;
#pragma unroll
        for (int w = 0; w < 8; ++w) {
            a += red[w * 3 + 0];
            b += red[w * 3 + 1];
            c += red[w * 3 + 2];
        }
        partials[blockIdx.x * 3 + 0] = a;   // sum log2(1+2^t)      (all)
        partials[blockIdx.x * 3 + 1] = b;   // sum log2(1+2^t)      (pos)
        partials[blockIdx.x * 3 + 2] = c;   // sum r                (pos)
    }
}

__global__ void finalize_kernel(const double* __restrict__ p,
                                float* __restrict__ out) {
    int t = threadIdx.x;  // 256 threads, one partial-triple each
    double a = p[t * 3 + 0], b = p[t * 3 + 1], c = p[t * 3 + 2];
#pragma unroll
    for (int off = 32; off; off >>= 1) {
        a += __shfl_xor(a, off);
        b += __shfl_xor(b, off);
        c += __shfl_xor(c, off);
    }
    __shared__ double red[12];
    int lane = t & 63, w = t >> 6;
    if (lane == 0) { red[w * 3] = a; red[w * 3 + 1] = b; red[w * 3 + 2] = c; }
    __syncthreads();
    if (t == 0) {
        double A = 0, B = 0, C = 0;
#pragma unroll
        for (int i = 0; i < 4; ++i) {
            A += red[i * 3]; B += red[i * 3 + 1]; C += red[i * 3 + 2];
        }
        const double NN = (double)N_NODES, GG = (double)N_GRAPHS;
        // q-sums: softplus(r) - ln2, with softplus = ln2 * l2
        double Sall_q = LN2 * A - NN * GG * LN2;  // all elements
        double Spq = LN2 * B - NN * LN2;          // pos elements (count = N)
        double Spr = C;
        double neg = (Sall_q - Spq) / (NN * (GG - 1.0));
        double pos = (Spr - Spq) / NN;
        out[0] = (float)(neg - pos);
    }
}

extern "C" void kernel_launch(void* const* d_in, const int* in_sizes, int n_in,
                              void* d_out, int out_size, void* d_ws,
                              size_t ws_size, hipStream_t stream) {
    const float* l_enc = (const float*)d_in[0];
    const float* g_enc = (const float*)d_in[1];
    const int* batch = (const int*)d_in[2];
    float* out = (float*)d_out;

    short* bpack = (short*)d_ws;                           // 128KB
    double* partials = (double*)((char*)d_ws + 131072);    // 256*3 doubles

    (void)hipFuncSetAttribute(reinterpret_cast<const void*>(mvgrl_main),
                              hipFuncAttributeMaxDynamicSharedMemorySize, 131072);

    pack_b_kernel<<<128, 64, 0, stream>>>(g_enc, bpack);
    mvgrl_main<<<256, 512, 131072, stream>>>(l_enc, batch, bpack, partials);
    finalize_kernel<<<1, 256, 0, stream>>>(partials, out);
}